// Round 1
// baseline (1037.048 us; speedup 1.0000x reference)
//
#include <hip/hip_runtime.h>

#define NGRAPH 256
#define NNODE  512
#define KNN    6
#define NF     64
#define ST     68                  // LDS row stride in floats: 272B, 16B-aligned
#define NT     256
#define EXTRA  (NNODE*ST)          // scratch region offset (floats)
#define LDS_FLOATS (EXTRA + 768)
#define LDS_BYTES  (LDS_FLOATS*4)  // 142336 B
#define BIG 1e30f

struct Params {
  const float *x;
  const float *W1,*b1,*a1, *W2,*b2,*a2;
  const float *Wc0,*bc0, *Wc1,*bc1, *Wc2,*bc2, *Wc3,*bc3;
  const float *W3,*b3,*a3, *W4,*b4,*a4;
  const float *Wh1,*bh1, *Wh2,*bh2, *Wh3,*bh3, *Wh4,*bh4;
  float *out;
};

// 64-feature row GEMM: acc[o] = sum_k row[k]*W[k*64+o].
// row is per-lane (LDS); W indices are wave-uniform -> scalar loads -> v_fmac v,s,v.
__device__ __forceinline__ void gemm64(const float* row, const float* W, float* acc) {
#pragma unroll
  for (int o = 0; o < NF; ++o) acc[o] = 0.f;
#pragma unroll 1
  for (int k4 = 0; k4 < 16; ++k4) {
    float4 xv = *(const float4*)(row + 4*k4);
    const float* w = W + 4*k4*NF;
#pragma unroll
    for (int o = 0; o < NF; ++o) acc[o] = fmaf(xv.x, w[o],        acc[o]);
#pragma unroll
    for (int o = 0; o < NF; ++o) acc[o] = fmaf(xv.y, w[NF+o],     acc[o]);
#pragma unroll
    for (int o = 0; o < NF; ++o) acc[o] = fmaf(xv.z, w[2*NF+o],   acc[o]);
#pragma unroll
    for (int o = 0; o < NF; ++o) acc[o] = fmaf(xv.w, w[3*NF+o],   acc[o]);
  }
}

// in-place row linear + PReLU
__device__ __forceinline__ void linear_row(float* lds, int r, const float* W,
                                           const float* b, const float* a) {
  float acc[NF];
  float* row = lds + r*ST;
  gemm64(row, W, acc);
#pragma unroll
  for (int o4 = 0; o4 < 16; ++o4) {
    float t0 = acc[4*o4+0] + b[4*o4+0];
    float t1 = acc[4*o4+1] + b[4*o4+1];
    float t2 = acc[4*o4+2] + b[4*o4+2];
    float t3 = acc[4*o4+3] + b[4*o4+3];
    float4 v;
    v.x = t0 >= 0.f ? t0 : a[4*o4+0]*t0;
    v.y = t1 >= 0.f ? t1 : a[4*o4+1]*t1;
    v.z = t2 >= 0.f ? t2 : a[4*o4+2]*t2;
    v.w = t3 >= 0.f ? t3 : a[4*o4+3]*t3;
    *(float4*)(row + 4*o4) = v;
  }
}

// sorted-ascending top-6 insert; strict < keeps earlier index on ties
__device__ __forceinline__ void insert6(float (&b)[KNN], int (&bi)[KNN], float v, int vi) {
  if (v < b[KNN-1]) {
#pragma unroll
    for (int p = 0; p < KNN; ++p) {
      bool lt = v < b[p];
      float tb = b[p]; int ti = bi[p];
      b[p]  = lt ? v  : tb;  bi[p] = lt ? vi : ti;
      v     = lt ? tb : v;   vi    = lt ? ti : vi;
    }
  }
}

__global__ __launch_bounds__(NT, 1) void fused_gnn(Params P) {
  extern __shared__ float lds[];
  const int tid = threadIdx.x;
  const int g   = blockIdx.x;

  // ---- stage x[g] (512x64) into LDS, coalesced float4 ----
  const float4* xg = (const float4*)(P.x + (size_t)g * NNODE * NF);
#pragma unroll 1
  for (int i = tid; i < NNODE*NF/4; i += NT) {
    float4 v = xg[i];
    int row = i >> 4, k4 = i & 15;
    *(float4*)&lds[row*ST + 4*k4] = v;
  }
  __syncthreads();

  const int q   = tid >> 1;           // 0..127
  const int jh  = tid & 1;            // j-half for knn
  const int rL0 = 4*q + 2*jh;         // rows owned in layer phases
  const int rL1 = rL0 + 1;

  // ---- sq[j] = |x_j|^2 into scratch ----
  {
    float s0 = 0.f, s1 = 0.f;
#pragma unroll
    for (int k4 = 0; k4 < 16; ++k4) {
      float4 a = *(const float4*)&lds[rL0*ST + 4*k4];
      float4 b = *(const float4*)&lds[rL1*ST + 4*k4];
      s0 = fmaf(a.x,a.x,s0); s0 = fmaf(a.y,a.y,s0); s0 = fmaf(a.z,a.z,s0); s0 = fmaf(a.w,a.w,s0);
      s1 = fmaf(b.x,b.x,s1); s1 = fmaf(b.y,b.y,s1); s1 = fmaf(b.z,b.z,s1); s1 = fmaf(b.w,b.w,s1);
    }
    lds[EXTRA + rL0] = s0;
    lds[EXTRA + rL1] = s1;
  }
  __syncthreads();

  // ---- kNN: thread scans rows 4q..4q+3 over j-half jh ----
  float best[4][KNN]; int bidx[4][KNN];
#pragma unroll
  for (int r = 0; r < 4; ++r)
#pragma unroll
    for (int m = 0; m < KNN; ++m) { best[r][m] = BIG; bidx[r][m] = 0; }

  float4 xr[4][16];
#pragma unroll
  for (int r = 0; r < 4; ++r)
#pragma unroll
    for (int k4 = 0; k4 < 16; ++k4)
      xr[r][k4] = *(const float4*)&lds[(4*q + r)*ST + 4*k4];

  const int jbase = jh * (NNODE/2);
  const int r0g   = 4*q;
#pragma unroll 1
  for (int jj = 0; jj < NNODE/2; ++jj) {
    int j = jbase + jj;
    const float* xj = &lds[j*ST];
    float4 a0 = {0,0,0,0}, a1 = {0,0,0,0}, a2 = {0,0,0,0}, a3 = {0,0,0,0};
#pragma unroll
    for (int k4 = 0; k4 < 16; ++k4) {
      float4 v = *(const float4*)(xj + 4*k4);   // wave-uniform address -> broadcast
      a0.x = fmaf(xr[0][k4].x, v.x, a0.x); a0.y = fmaf(xr[0][k4].y, v.y, a0.y);
      a0.z = fmaf(xr[0][k4].z, v.z, a0.z); a0.w = fmaf(xr[0][k4].w, v.w, a0.w);
      a1.x = fmaf(xr[1][k4].x, v.x, a1.x); a1.y = fmaf(xr[1][k4].y, v.y, a1.y);
      a1.z = fmaf(xr[1][k4].z, v.z, a1.z); a1.w = fmaf(xr[1][k4].w, v.w, a1.w);
      a2.x = fmaf(xr[2][k4].x, v.x, a2.x); a2.y = fmaf(xr[2][k4].y, v.y, a2.y);
      a2.z = fmaf(xr[2][k4].z, v.z, a2.z); a2.w = fmaf(xr[2][k4].w, v.w, a2.w);
      a3.x = fmaf(xr[3][k4].x, v.x, a3.x); a3.y = fmaf(xr[3][k4].y, v.y, a3.y);
      a3.z = fmaf(xr[3][k4].z, v.z, a3.z); a3.w = fmaf(xr[3][k4].w, v.w, a3.w);
    }
    float sj = lds[EXTRA + j];
    float e0 = fmaf(-2.f, (a0.x+a0.y)+(a0.z+a0.w), sj);
    float e1 = fmaf(-2.f, (a1.x+a1.y)+(a1.z+a1.w), sj);
    float e2 = fmaf(-2.f, (a2.x+a2.y)+(a2.z+a2.w), sj);
    float e3 = fmaf(-2.f, (a3.x+a3.y)+(a3.z+a3.w), sj);
    if (j == r0g)   e0 = BIG;
    if (j == r0g+1) e1 = BIG;
    if (j == r0g+2) e2 = BIG;
    if (j == r0g+3) e3 = BIG;
    insert6(best[0], bidx[0], e0, j);
    insert6(best[1], bidx[1], e1, j);
    insert6(best[2], bidx[2], e2, j);
    insert6(best[3], bidx[3], e3, j);
  }

  // ---- merge top-6 with partner lane (other j-half); snapshot first ----
#pragma unroll
  for (int r = 0; r < 4; ++r) {
    float pv[KNN]; int pi[KNN];
#pragma unroll
    for (int m = 0; m < KNN; ++m) {
      pv[m] = __shfl_xor(best[r][m], 1);
      pi[m] = __shfl_xor(bidx[r][m], 1);
    }
#pragma unroll
    for (int m = 0; m < KNN; ++m) insert6(best[r], bidx[r], pv[m], pi[m]);
  }

  // neighbor lists for the 2 rows this thread owns in layer phases
  int nbr0[KNN], nbr1[KNN];
#pragma unroll
  for (int m = 0; m < KNN; ++m) {
    nbr0[m] = jh ? bidx[2][m] : bidx[0][m];
    nbr1[m] = jh ? bidx[3][m] : bidx[1][m];
  }

  __syncthreads();   // everyone done reading x before h overwrites it

  // ---- h = prelu(x@W1+b1); h = prelu(h@W2+b2)  (row-local, in place) ----
  linear_row(lds, rL0, P.W1, P.b1, P.a1);
  linear_row(lds, rL1, P.W1, P.b1, P.a1);
  linear_row(lds, rL0, P.W2, P.b2, P.a2);
  linear_row(lds, rL1, P.W2, P.b2, P.a2);

  // ---- 4x gconv: out_i = sum_{m in nbr} (h@W)_m + 6b + h_i ----
  const float* Wcs[4] = {P.Wc0, P.Wc1, P.Wc2, P.Wc3};
  const float* bcs[4] = {P.bc0, P.bc1, P.bc2, P.bc3};
#pragma unroll 1
  for (int cv = 0; cv < 4; ++cv) {
    const float* W = Wcs[cv];
    const float* b = bcs[cv];
    __syncthreads();                       // h stable everywhere
    float hs0[NF], hs1[NF];
#pragma unroll
    for (int k4 = 0; k4 < 16; ++k4) {
      float4 v = *(const float4*)&lds[rL0*ST + 4*k4];
      hs0[4*k4]=v.x; hs0[4*k4+1]=v.y; hs0[4*k4+2]=v.z; hs0[4*k4+3]=v.w;
      float4 u = *(const float4*)&lds[rL1*ST + 4*k4];
      hs1[4*k4]=u.x; hs1[4*k4+1]=u.y; hs1[4*k4+2]=u.z; hs1[4*k4+3]=u.w;
    }
    {
      float p0[NF];
      gemm64(&lds[rL0*ST], W, p0);
#pragma unroll
      for (int o4 = 0; o4 < 16; ++o4) {
        float4 v = {p0[4*o4], p0[4*o4+1], p0[4*o4+2], p0[4*o4+3]};
        *(float4*)&lds[rL0*ST + 4*o4] = v;
      }
    }
    {
      float p1[NF];
      gemm64(&lds[rL1*ST], W, p1);
#pragma unroll
      for (int o4 = 0; o4 < 16; ++o4) {
        float4 v = {p1[4*o4], p1[4*o4+1], p1[4*o4+2], p1[4*o4+3]};
        *(float4*)&lds[rL1*ST + 4*o4] = v;
      }
    }
    __syncthreads();                       // all p-rows published
    float s0[NF], s1[NF];
#pragma unroll
    for (int o = 0; o < NF; ++o) { s0[o] = 0.f; s1[o] = 0.f; }
#pragma unroll
    for (int m = 0; m < KNN; ++m) {
      const float* pr = &lds[nbr0[m]*ST];
#pragma unroll
      for (int o4 = 0; o4 < 16; ++o4) {
        float4 v = *(const float4*)(pr + 4*o4);
        s0[4*o4]+=v.x; s0[4*o4+1]+=v.y; s0[4*o4+2]+=v.z; s0[4*o4+3]+=v.w;
      }
    }
#pragma unroll
    for (int m = 0; m < KNN; ++m) {
      const float* pr = &lds[nbr1[m]*ST];
#pragma unroll
      for (int o4 = 0; o4 < 16; ++o4) {
        float4 v = *(const float4*)(pr + 4*o4);
        s1[4*o4]+=v.x; s1[4*o4+1]+=v.y; s1[4*o4+2]+=v.z; s1[4*o4+3]+=v.w;
      }
    }
    __syncthreads();                       // all gathers done before overwrite
#pragma unroll
    for (int o4 = 0; o4 < 16; ++o4) {
      float4 v;
      v.x = s0[4*o4]   + 6.f*b[4*o4]   + hs0[4*o4];
      v.y = s0[4*o4+1] + 6.f*b[4*o4+1] + hs0[4*o4+1];
      v.z = s0[4*o4+2] + 6.f*b[4*o4+2] + hs0[4*o4+2];
      v.w = s0[4*o4+3] + 6.f*b[4*o4+3] + hs0[4*o4+3];
      *(float4*)&lds[rL0*ST + 4*o4] = v;
    }
#pragma unroll
    for (int o4 = 0; o4 < 16; ++o4) {
      float4 v;
      v.x = s1[4*o4]   + 6.f*b[4*o4]   + hs1[4*o4];
      v.y = s1[4*o4+1] + 6.f*b[4*o4+1] + hs1[4*o4+1];
      v.z = s1[4*o4+2] + 6.f*b[4*o4+2] + hs1[4*o4+2];
      v.w = s1[4*o4+3] + 6.f*b[4*o4+3] + hs1[4*o4+3];
      *(float4*)&lds[rL1*ST + 4*o4] = v;
    }
  }

  // ---- last two PReLU linears (row-local) ----
  linear_row(lds, rL0, P.W3, P.b3, P.a3);
  linear_row(lds, rL1, P.W3, P.b3, P.a3);
  linear_row(lds, rL0, P.W4, P.b4, P.a4);
  linear_row(lds, rL1, P.W4, P.b4, P.a4);

  __syncthreads();

  // ---- global add pool: pooled[f] = sum_rows h[r][f] ----
  {
    int f = tid & 63, c = tid >> 6;
    int rstart = c * 128;
    float pa=0.f, pb=0.f, pc=0.f, pd=0.f;
#pragma unroll 1
    for (int r = 0; r < 128; r += 4) {
      pa += lds[(rstart+r  )*ST + f];
      pb += lds[(rstart+r+1)*ST + f];
      pc += lds[(rstart+r+2)*ST + f];
      pd += lds[(rstart+r+3)*ST + f];
    }
    lds[EXTRA + 64 + c*64 + f] = (pa+pb)+(pc+pd);
  }
  __syncthreads();
  if (tid < 64) {
    float pool = lds[EXTRA+64+tid] + lds[EXTRA+128+tid]
               + lds[EXTRA+192+tid] + lds[EXTRA+256+tid];
    lds[EXTRA + tid] = pool;               // pooled[0..63]
  }
  __syncthreads();

  // ---- head MLP ----
  {                                        // y1 = leaky(pooled @ Wh1 + bh1), 256 wide
    float acc = P.bh1[tid];
#pragma unroll 4
    for (int k = 0; k < 64; ++k) acc = fmaf(lds[EXTRA+k], P.Wh1[k*256 + tid], acc);
    lds[EXTRA + 64 + tid] = acc >= 0.f ? acc : 0.2f*acc;   // y1 @ EXTRA+64..319
  }
  __syncthreads();
  {                                        // y2 = leaky(y1 @ Wh2 + bh2), 256 wide
    float acc = P.bh2[tid];
#pragma unroll 4
    for (int k = 0; k < 256; ++k) acc = fmaf(lds[EXTRA+64+k], P.Wh2[k*256 + tid], acc);
    lds[EXTRA + 320 + tid] = acc >= 0.f ? acc : 0.2f*acc;  // y2 @ EXTRA+320..575
  }
  __syncthreads();
  if (tid < 64) {                          // y3 = leaky(y2 @ Wh3 + bh3), 64 wide
    float acc = P.bh3[tid];
#pragma unroll 4
    for (int k = 0; k < 256; ++k) acc = fmaf(lds[EXTRA+320+k], P.Wh3[k*64 + tid], acc);
    lds[EXTRA + 576 + tid] = acc >= 0.f ? acc : 0.2f*acc;
  }
  __syncthreads();
  if (tid == 0) {                          // out[g] = y3 @ Wh4 + bh4
    float acc = P.bh4[0];
#pragma unroll 4
    for (int k = 0; k < 64; ++k) acc = fmaf(lds[EXTRA+576+k], P.Wh4[k], acc);
    P.out[g] = acc;
  }
}

extern "C" void kernel_launch(void* const* d_in, const int* in_sizes, int n_in,
                              void* d_out, int out_size, void* d_ws, size_t ws_size,
                              hipStream_t stream) {
  Params P;
  P.x   = (const float*)d_in[0];
  P.W1  = (const float*)d_in[1];  P.b1  = (const float*)d_in[2];  P.a1 = (const float*)d_in[3];
  P.W2  = (const float*)d_in[4];  P.b2  = (const float*)d_in[5];  P.a2 = (const float*)d_in[6];
  P.Wc0 = (const float*)d_in[7];  P.bc0 = (const float*)d_in[8];
  P.Wc1 = (const float*)d_in[9];  P.bc1 = (const float*)d_in[10];
  P.Wc2 = (const float*)d_in[11]; P.bc2 = (const float*)d_in[12];
  P.Wc3 = (const float*)d_in[13]; P.bc3 = (const float*)d_in[14];
  P.W3  = (const float*)d_in[15]; P.b3  = (const float*)d_in[16]; P.a3 = (const float*)d_in[17];
  P.W4  = (const float*)d_in[18]; P.b4  = (const float*)d_in[19]; P.a4 = (const float*)d_in[20];
  P.Wh1 = (const float*)d_in[21]; P.bh1 = (const float*)d_in[22];
  P.Wh2 = (const float*)d_in[23]; P.bh2 = (const float*)d_in[24];
  P.Wh3 = (const float*)d_in[25]; P.bh3 = (const float*)d_in[26];
  P.Wh4 = (const float*)d_in[27]; P.bh4 = (const float*)d_in[28];
  P.out = (float*)d_out;

  // opt-in for >64KB dynamic LDS (142336 B); idempotent, graph-capture safe
  (void)hipFuncSetAttribute(reinterpret_cast<const void*>(fused_gnn),
                            hipFuncAttributeMaxDynamicSharedMemorySize, LDS_BYTES);

  fused_gnn<<<NGRAPH, NT, LDS_BYTES, stream>>>(P);
}

// Round 2
// 1003.309 us; speedup vs baseline: 1.0336x; 1.0336x over previous
//
#include <hip/hip_runtime.h>

#define NGRAPH 256
#define NNODE  512
#define KNN    6
#define NF     64
#define ST     68                  // LDS row stride in floats: 272B, 16B-aligned
#define NT     256
#define EXTRA  (NNODE*ST)          // scratch region offset (floats): 34816
#define IDXOFF (EXTRA + 768)       // knn index lists (ints), 512*6 = 3072
#define LDS_FLOATS (IDXOFF + 3072) // 38656 floats
#define LDS_BYTES  (LDS_FLOATS*4)  // 154624 B  (< 160 KiB)
#define BIG 1e30f

struct Params {
  const float *x;
  const float *W1,*b1,*a1, *W2,*b2,*a2;
  const float *Wc0,*bc0, *Wc1,*bc1, *Wc2,*bc2, *Wc3,*bc3;
  const float *W3,*b3,*a3, *W4,*b4,*a4;
  const float *Wh1,*bh1, *Wh2,*bh2, *Wh3,*bh3, *Wh4,*bh4;
  float *out;
};

// 64-feature row GEMM: acc[o] = sum_k row[k]*W[k*64+o].
// row is per-lane (LDS); W indices are wave-uniform -> scalar loads -> v_fmac v,s,v.
__device__ __forceinline__ void gemm64(const float* row, const float* W, float* acc) {
#pragma unroll
  for (int o = 0; o < NF; ++o) acc[o] = 0.f;
#pragma unroll 1
  for (int k4 = 0; k4 < 16; ++k4) {
    float4 xv = *(const float4*)(row + 4*k4);
    const float* w = W + 4*k4*NF;
#pragma unroll
    for (int o = 0; o < NF; ++o) acc[o] = fmaf(xv.x, w[o],        acc[o]);
#pragma unroll
    for (int o = 0; o < NF; ++o) acc[o] = fmaf(xv.y, w[NF+o],     acc[o]);
#pragma unroll
    for (int o = 0; o < NF; ++o) acc[o] = fmaf(xv.z, w[2*NF+o],   acc[o]);
#pragma unroll
    for (int o = 0; o < NF; ++o) acc[o] = fmaf(xv.w, w[3*NF+o],   acc[o]);
  }
}

// in-place row linear + PReLU
__device__ __forceinline__ void linear_row(float* lds, int r, const float* W,
                                           const float* b, const float* a) {
  float acc[NF];
  float* row = lds + r*ST;
  gemm64(row, W, acc);
#pragma unroll
  for (int o4 = 0; o4 < 16; ++o4) {
    float t0 = acc[4*o4+0] + b[4*o4+0];
    float t1 = acc[4*o4+1] + b[4*o4+1];
    float t2 = acc[4*o4+2] + b[4*o4+2];
    float t3 = acc[4*o4+3] + b[4*o4+3];
    float4 v;
    v.x = t0 >= 0.f ? t0 : a[4*o4+0]*t0;
    v.y = t1 >= 0.f ? t1 : a[4*o4+1]*t1;
    v.z = t2 >= 0.f ? t2 : a[4*o4+2]*t2;
    v.w = t3 >= 0.f ? t3 : a[4*o4+3]*t3;
    *(float4*)(row + 4*o4) = v;
  }
}

// sorted-ascending top-6 insert; strict < keeps earlier index on ties
__device__ __forceinline__ void insert6(float (&b)[KNN], int (&bi)[KNN], float v, int vi) {
  if (v < b[KNN-1]) {
#pragma unroll
    for (int p = 0; p < KNN; ++p) {
      bool lt = v < b[p];
      float tb = b[p]; int ti = bi[p];
      b[p]  = lt ? v  : tb;  bi[p] = lt ? vi : ti;
      v     = lt ? tb : v;   vi    = lt ? ti : vi;
    }
  }
}

__global__ __launch_bounds__(NT, 1) void fused_gnn(Params P) {
  extern __shared__ float lds[];
  int* ildx = (int*)&lds[IDXOFF];
  const int tid = threadIdx.x;
  const int g   = blockIdx.x;

  // ---- stage x[g] (512x64) into LDS, coalesced float4 ----
  const float4* xg = (const float4*)(P.x + (size_t)g * NNODE * NF);
#pragma unroll 1
  for (int i = tid; i < NNODE*NF/4; i += NT) {
    float4 v = xg[i];
    int row = i >> 4, k4 = i & 15;
    *(float4*)&lds[row*ST + 4*k4] = v;
  }
  __syncthreads();

  // layer-phase row ownership: consecutive rows per wave -> balanced LDS banks
  const int rA = tid;
  const int rB = tid + 256;

  // ---- sq[j] = |x_j|^2 into scratch ----
  {
    float s0 = 0.f, s1 = 0.f;
#pragma unroll
    for (int k4 = 0; k4 < 16; ++k4) {
      float4 a = *(const float4*)&lds[rA*ST + 4*k4];
      float4 b = *(const float4*)&lds[rB*ST + 4*k4];
      s0 = fmaf(a.x,a.x,s0); s0 = fmaf(a.y,a.y,s0); s0 = fmaf(a.z,a.z,s0); s0 = fmaf(a.w,a.w,s0);
      s1 = fmaf(b.x,b.x,s1); s1 = fmaf(b.y,b.y,s1); s1 = fmaf(b.z,b.z,s1); s1 = fmaf(b.w,b.w,s1);
    }
    lds[EXTRA + rA] = s0;
    lds[EXTRA + rB] = s1;
  }
  __syncthreads();

  // ---- kNN: thread scans rows 4q..4q+3 over j-half jh (proven-exact mapping) ----
  const int q   = tid >> 1;           // 0..127
  const int jh  = tid & 1;            // j-half for knn

  float best[4][KNN]; int bidx[4][KNN];
#pragma unroll
  for (int r = 0; r < 4; ++r)
#pragma unroll
    for (int m = 0; m < KNN; ++m) { best[r][m] = BIG; bidx[r][m] = 0; }

  float4 xr[4][16];
#pragma unroll
  for (int r = 0; r < 4; ++r)
#pragma unroll
    for (int k4 = 0; k4 < 16; ++k4)
      xr[r][k4] = *(const float4*)&lds[(4*q + r)*ST + 4*k4];

  const int jbase = jh * (NNODE/2);
  const int r0g   = 4*q;
#pragma unroll 1
  for (int jj = 0; jj < NNODE/2; ++jj) {
    int j = jbase + jj;
    const float* xj = &lds[j*ST];
    float4 a0 = {0,0,0,0}, a1 = {0,0,0,0}, a2 = {0,0,0,0}, a3 = {0,0,0,0};
#pragma unroll
    for (int k4 = 0; k4 < 16; ++k4) {
      float4 v = *(const float4*)(xj + 4*k4);   // 2-address broadcast (free)
      a0.x = fmaf(xr[0][k4].x, v.x, a0.x); a0.y = fmaf(xr[0][k4].y, v.y, a0.y);
      a0.z = fmaf(xr[0][k4].z, v.z, a0.z); a0.w = fmaf(xr[0][k4].w, v.w, a0.w);
      a1.x = fmaf(xr[1][k4].x, v.x, a1.x); a1.y = fmaf(xr[1][k4].y, v.y, a1.y);
      a1.z = fmaf(xr[1][k4].z, v.z, a1.z); a1.w = fmaf(xr[1][k4].w, v.w, a1.w);
      a2.x = fmaf(xr[2][k4].x, v.x, a2.x); a2.y = fmaf(xr[2][k4].y, v.y, a2.y);
      a2.z = fmaf(xr[2][k4].z, v.z, a2.z); a2.w = fmaf(xr[2][k4].w, v.w, a2.w);
      a3.x = fmaf(xr[3][k4].x, v.x, a3.x); a3.y = fmaf(xr[3][k4].y, v.y, a3.y);
      a3.z = fmaf(xr[3][k4].z, v.z, a3.z); a3.w = fmaf(xr[3][k4].w, v.w, a3.w);
    }
    float sj = lds[EXTRA + j];
    float e0 = fmaf(-2.f, (a0.x+a0.y)+(a0.z+a0.w), sj);
    float e1 = fmaf(-2.f, (a1.x+a1.y)+(a1.z+a1.w), sj);
    float e2 = fmaf(-2.f, (a2.x+a2.y)+(a2.z+a2.w), sj);
    float e3 = fmaf(-2.f, (a3.x+a3.y)+(a3.z+a3.w), sj);
    if (j == r0g)   e0 = BIG;
    if (j == r0g+1) e1 = BIG;
    if (j == r0g+2) e2 = BIG;
    if (j == r0g+3) e3 = BIG;
    insert6(best[0], bidx[0], e0, j);
    insert6(best[1], bidx[1], e1, j);
    insert6(best[2], bidx[2], e2, j);
    insert6(best[3], bidx[3], e3, j);
  }

  // ---- merge top-6 with partner lane (other j-half); snapshot first ----
#pragma unroll
  for (int r = 0; r < 4; ++r) {
    float pv[KNN]; int pi[KNN];
#pragma unroll
    for (int m = 0; m < KNN; ++m) {
      pv[m] = __shfl_xor(best[r][m], 1);
      pi[m] = __shfl_xor(bidx[r][m], 1);
    }
#pragma unroll
    for (int m = 0; m < KNN; ++m) insert6(best[r], bidx[r], pv[m], pi[m]);
  }

  // ---- publish canonical neighbor lists (jh==0 lanes) to LDS idx area ----
  if (jh == 0) {
#pragma unroll
    for (int r = 0; r < 4; ++r)
#pragma unroll
      for (int m = 0; m < KNN; ++m)
        ildx[(4*q + r)*KNN + m] = bidx[r][m];
  }
  __syncthreads();

  // owners pick up their rows' neighbor lists
  int nbrA[KNN], nbrB[KNN];
#pragma unroll
  for (int m = 0; m < KNN; ++m) {
    nbrA[m] = ildx[rA*KNN + m];
    nbrB[m] = ildx[rB*KNN + m];
  }

  // ---- h = prelu(x@W1+b1); h = prelu(h@W2+b2)  (own rows, in place) ----
  linear_row(lds, rA, P.W1, P.b1, P.a1);
  linear_row(lds, rB, P.W1, P.b1, P.a1);
  linear_row(lds, rA, P.W2, P.b2, P.a2);
  linear_row(lds, rB, P.W2, P.b2, P.a2);

  // ---- 4x gconv: out_i = sum_{m in nbr} (h@W)_m + 6b + h_i ----
  const float* Wcs[4] = {P.Wc0, P.Wc1, P.Wc2, P.Wc3};
  const float* bcs[4] = {P.bc0, P.bc1, P.bc2, P.bc3};
#pragma unroll 1
  for (int cv = 0; cv < 4; ++cv) {
    const float* W = Wcs[cv];
    const float* b = bcs[cv];
    // snapshot own h rows (own-thread RAW, no barrier needed)
    float hsA[NF], hsB[NF];
#pragma unroll
    for (int k4 = 0; k4 < 16; ++k4) {
      float4 v = *(const float4*)&lds[rA*ST + 4*k4];
      hsA[4*k4]=v.x; hsA[4*k4+1]=v.y; hsA[4*k4+2]=v.z; hsA[4*k4+3]=v.w;
      float4 u = *(const float4*)&lds[rB*ST + 4*k4];
      hsB[4*k4]=u.x; hsB[4*k4+1]=u.y; hsB[4*k4+2]=u.z; hsB[4*k4+3]=u.w;
    }
    // p = h @ W, published in place
    {
      float p0[NF];
      gemm64(&lds[rA*ST], W, p0);
#pragma unroll
      for (int o4 = 0; o4 < 16; ++o4) {
        float4 v = {p0[4*o4], p0[4*o4+1], p0[4*o4+2], p0[4*o4+3]};
        *(float4*)&lds[rA*ST + 4*o4] = v;
      }
    }
    {
      float p1[NF];
      gemm64(&lds[rB*ST], W, p1);
#pragma unroll
      for (int o4 = 0; o4 < 16; ++o4) {
        float4 v = {p1[4*o4], p1[4*o4+1], p1[4*o4+2], p1[4*o4+3]};
        *(float4*)&lds[rB*ST + 4*o4] = v;
      }
    }
    __syncthreads();                       // all p-rows published
    // gather: s = sum of 6 neighbor p-rows (init from neighbor 0)
    float sA[NF], sB[NF];
    {
      const float* pr = &lds[nbrA[0]*ST];
#pragma unroll
      for (int o4 = 0; o4 < 16; ++o4) {
        float4 v = *(const float4*)(pr + 4*o4);
        sA[4*o4]=v.x; sA[4*o4+1]=v.y; sA[4*o4+2]=v.z; sA[4*o4+3]=v.w;
      }
    }
#pragma unroll
    for (int m = 1; m < KNN; ++m) {
      const float* pr = &lds[nbrA[m]*ST];
#pragma unroll
      for (int o4 = 0; o4 < 16; ++o4) {
        float4 v = *(const float4*)(pr + 4*o4);
        sA[4*o4]+=v.x; sA[4*o4+1]+=v.y; sA[4*o4+2]+=v.z; sA[4*o4+3]+=v.w;
      }
    }
    {
      const float* pr = &lds[nbrB[0]*ST];
#pragma unroll
      for (int o4 = 0; o4 < 16; ++o4) {
        float4 v = *(const float4*)(pr + 4*o4);
        sB[4*o4]=v.x; sB[4*o4+1]=v.y; sB[4*o4+2]=v.z; sB[4*o4+3]=v.w;
      }
    }
#pragma unroll
    for (int m = 1; m < KNN; ++m) {
      const float* pr = &lds[nbrB[m]*ST];
#pragma unroll
      for (int o4 = 0; o4 < 16; ++o4) {
        float4 v = *(const float4*)(pr + 4*o4);
        sB[4*o4]+=v.x; sB[4*o4+1]+=v.y; sB[4*o4+2]+=v.z; sB[4*o4+3]+=v.w;
      }
    }
    __syncthreads();                       // all gathers done before overwrite
#pragma unroll
    for (int o4 = 0; o4 < 16; ++o4) {
      float4 v;
      v.x = sA[4*o4]   + 6.f*b[4*o4]   + hsA[4*o4];
      v.y = sA[4*o4+1] + 6.f*b[4*o4+1] + hsA[4*o4+1];
      v.z = sA[4*o4+2] + 6.f*b[4*o4+2] + hsA[4*o4+2];
      v.w = sA[4*o4+3] + 6.f*b[4*o4+3] + hsA[4*o4+3];
      *(float4*)&lds[rA*ST + 4*o4] = v;
    }
#pragma unroll
    for (int o4 = 0; o4 < 16; ++o4) {
      float4 v;
      v.x = sB[4*o4]   + 6.f*b[4*o4]   + hsB[4*o4];
      v.y = sB[4*o4+1] + 6.f*b[4*o4+1] + hsB[4*o4+1];
      v.z = sB[4*o4+2] + 6.f*b[4*o4+2] + hsB[4*o4+2];
      v.w = sB[4*o4+3] + 6.f*b[4*o4+3] + hsB[4*o4+3];
      *(float4*)&lds[rB*ST + 4*o4] = v;
    }
  }

  // ---- last two PReLU linears (own rows) ----
  linear_row(lds, rA, P.W3, P.b3, P.a3);
  linear_row(lds, rB, P.W3, P.b3, P.a3);
  linear_row(lds, rA, P.W4, P.b4, P.a4);
  linear_row(lds, rB, P.W4, P.b4, P.a4);

  __syncthreads();   // all h final before pool reads

  // ---- global add pool: pooled[f] = sum_rows h[r][f] ----
  {
    int f = tid & 63, c = tid >> 6;
    int rstart = c * 128;
    float pa=0.f, pb=0.f, pc=0.f, pd=0.f;
#pragma unroll 1
    for (int r = 0; r < 128; r += 4) {
      pa += lds[(rstart+r  )*ST + f];
      pb += lds[(rstart+r+1)*ST + f];
      pc += lds[(rstart+r+2)*ST + f];
      pd += lds[(rstart+r+3)*ST + f];
    }
    lds[EXTRA + 64 + c*64 + f] = (pa+pb)+(pc+pd);
  }
  __syncthreads();
  if (tid < 64) {
    float pool = lds[EXTRA+64+tid] + lds[EXTRA+128+tid]
               + lds[EXTRA+192+tid] + lds[EXTRA+256+tid];
    lds[EXTRA + tid] = pool;               // pooled[0..63]
  }
  __syncthreads();

  // ---- head MLP ----
  {                                        // y1 = leaky(pooled @ Wh1 + bh1), 256 wide
    float acc = P.bh1[tid];
#pragma unroll 4
    for (int k = 0; k < 64; ++k) acc = fmaf(lds[EXTRA+k], P.Wh1[k*256 + tid], acc);
    lds[EXTRA + 64 + tid] = acc >= 0.f ? acc : 0.2f*acc;   // y1 @ EXTRA+64..319
  }
  __syncthreads();
  {                                        // y2 = leaky(y1 @ Wh2 + bh2), 256 wide
    float acc = P.bh2[tid];
#pragma unroll 4
    for (int k = 0; k < 256; ++k) acc = fmaf(lds[EXTRA+64+k], P.Wh2[k*256 + tid], acc);
    lds[EXTRA + 320 + tid] = acc >= 0.f ? acc : 0.2f*acc;  // y2 @ EXTRA+320..575
  }
  __syncthreads();
  if (tid < 64) {                          // y3 = leaky(y2 @ Wh3 + bh3), 64 wide
    float acc = P.bh3[tid];
#pragma unroll 4
    for (int k = 0; k < 256; ++k) acc = fmaf(lds[EXTRA+320+k], P.Wh3[k*64 + tid], acc);
    lds[EXTRA + 576 + tid] = acc >= 0.f ? acc : 0.2f*acc;
  }
  __syncthreads();
  if (tid == 0) {                          // out[g] = y3 @ Wh4 + bh4
    float acc = P.bh4[0];
#pragma unroll 4
    for (int k = 0; k < 64; ++k) acc = fmaf(lds[EXTRA+576+k], P.Wh4[k], acc);
    P.out[g] = acc;
  }
}

extern "C" void kernel_launch(void* const* d_in, const int* in_sizes, int n_in,
                              void* d_out, int out_size, void* d_ws, size_t ws_size,
                              hipStream_t stream) {
  Params P;
  P.x   = (const float*)d_in[0];
  P.W1  = (const float*)d_in[1];  P.b1  = (const float*)d_in[2];  P.a1 = (const float*)d_in[3];
  P.W2  = (const float*)d_in[4];  P.b2  = (const float*)d_in[5];  P.a2 = (const float*)d_in[6];
  P.Wc0 = (const float*)d_in[7];  P.bc0 = (const float*)d_in[8];
  P.Wc1 = (const float*)d_in[9];  P.bc1 = (const float*)d_in[10];
  P.Wc2 = (const float*)d_in[11]; P.bc2 = (const float*)d_in[12];
  P.Wc3 = (const float*)d_in[13]; P.bc3 = (const float*)d_in[14];
  P.W3  = (const float*)d_in[15]; P.b3  = (const float*)d_in[16]; P.a3 = (const float*)d_in[17];
  P.W4  = (const float*)d_in[18]; P.b4  = (const float*)d_in[19]; P.a4 = (const float*)d_in[20];
  P.Wh1 = (const float*)d_in[21]; P.bh1 = (const float*)d_in[22];
  P.Wh2 = (const float*)d_in[23]; P.bh2 = (const float*)d_in[24];
  P.Wh3 = (const float*)d_in[25]; P.bh3 = (const float*)d_in[26];
  P.Wh4 = (const float*)d_in[27]; P.bh4 = (const float*)d_in[28];
  P.out = (float*)d_out;

  // opt-in for >64KB dynamic LDS (154624 B); idempotent, graph-capture safe
  (void)hipFuncSetAttribute(reinterpret_cast<const void*>(fused_gnn),
                            hipFuncAttributeMaxDynamicSharedMemorySize, LDS_BYTES);

  fused_gnn<<<NGRAPH, NT, LDS_BYTES, stream>>>(P);
}

// Round 3
// 849.235 us; speedup vs baseline: 1.2212x; 1.1814x over previous
//
#include <hip/hip_runtime.h>

#define NGRAPH 256
#define NNODE  512
#define KNN    6
#define NF     64
#define ST     68                  // LDS row stride in floats: 272B, 16B-aligned
#define NT     512
#define EXTRA  (NNODE*ST)          // scratch region offset (floats): 34816
#define IDXOFF (EXTRA + 768)       // knn index lists (ints), 512*6 = 3072
#define LDS_FLOATS (IDXOFF + 3072) // 38656 floats
#define LDS_BYTES  (LDS_FLOATS*4)  // 154624 B  (< 160 KiB)
#define BIG 1e30f

struct Params {
  const float *x;
  const float *W1,*b1,*a1, *W2,*b2,*a2;
  const float *Wc0,*bc0, *Wc1,*bc1, *Wc2,*bc2, *Wc3,*bc3;
  const float *W3,*b3,*a3, *W4,*b4,*a4;
  const float *Wh1,*bh1, *Wh2,*bh2, *Wh3,*bh3, *Wh4,*bh4;
  float *out;
};

// 64-feature row GEMM: acc[o] = sum_k row[k]*W[k*64+o].
// row is per-lane (LDS); W indices are wave-uniform -> scalar loads -> v_fmac v,s,v.
__device__ __forceinline__ void gemm64(const float* row, const float* W, float* acc) {
#pragma unroll
  for (int o = 0; o < NF; ++o) acc[o] = 0.f;
#pragma unroll 1
  for (int k4 = 0; k4 < 16; ++k4) {
    float4 xv = *(const float4*)(row + 4*k4);
    const float* w = W + 4*k4*NF;
#pragma unroll
    for (int o = 0; o < NF; ++o) acc[o] = fmaf(xv.x, w[o],        acc[o]);
#pragma unroll
    for (int o = 0; o < NF; ++o) acc[o] = fmaf(xv.y, w[NF+o],     acc[o]);
#pragma unroll
    for (int o = 0; o < NF; ++o) acc[o] = fmaf(xv.z, w[2*NF+o],   acc[o]);
#pragma unroll
    for (int o = 0; o < NF; ++o) acc[o] = fmaf(xv.w, w[3*NF+o],   acc[o]);
  }
}

// in-place row linear + PReLU
__device__ __forceinline__ void linear_row(float* lds, int r, const float* W,
                                           const float* b, const float* a) {
  float acc[NF];
  float* row = lds + r*ST;
  gemm64(row, W, acc);
#pragma unroll
  for (int o4 = 0; o4 < 16; ++o4) {
    float t0 = acc[4*o4+0] + b[4*o4+0];
    float t1 = acc[4*o4+1] + b[4*o4+1];
    float t2 = acc[4*o4+2] + b[4*o4+2];
    float t3 = acc[4*o4+3] + b[4*o4+3];
    float4 v;
    v.x = t0 >= 0.f ? t0 : a[4*o4+0]*t0;
    v.y = t1 >= 0.f ? t1 : a[4*o4+1]*t1;
    v.z = t2 >= 0.f ? t2 : a[4*o4+2]*t2;
    v.w = t3 >= 0.f ? t3 : a[4*o4+3]*t3;
    *(float4*)(row + 4*o4) = v;
  }
}

// sorted-ascending top-6 insert; strict < keeps earlier index on ties
__device__ __forceinline__ void insert6(float (&b)[KNN], int (&bi)[KNN], float v, int vi) {
  if (v < b[KNN-1]) {
#pragma unroll
    for (int p = 0; p < KNN; ++p) {
      bool lt = v < b[p];
      float tb = b[p]; int ti = bi[p];
      b[p]  = lt ? v  : tb;  bi[p] = lt ? vi : ti;
      v     = lt ? tb : v;   vi    = lt ? ti : vi;
    }
  }
}

__global__ __launch_bounds__(NT, 2) void fused_gnn(Params P) {
  extern __shared__ float lds[];
  int* ildx = (int*)&lds[IDXOFF];
  const int tid = threadIdx.x;
  const int g   = blockIdx.x;

  // ---- stage x[g] (512x64) into LDS, coalesced float4 ----
  const float4* xg = (const float4*)(P.x + (size_t)g * NNODE * NF);
#pragma unroll 1
  for (int i = tid; i < NNODE*NF/4; i += NT) {
    float4 v = xg[i];
    int row = i >> 4, k4 = i & 15;
    *(float4*)&lds[row*ST + 4*k4] = v;
  }
  __syncthreads();

  // layer-phase row ownership: 1 row per thread
  const int rA = tid;

  // ---- sq[j] = |x_j|^2 into scratch ----
  {
    float s0 = 0.f;
#pragma unroll
    for (int k4 = 0; k4 < 16; ++k4) {
      float4 a = *(const float4*)&lds[rA*ST + 4*k4];
      s0 = fmaf(a.x,a.x,s0); s0 = fmaf(a.y,a.y,s0); s0 = fmaf(a.z,a.z,s0); s0 = fmaf(a.w,a.w,s0);
    }
    lds[EXTRA + rA] = s0;
  }
  __syncthreads();

  // ---- kNN: thread owns rows 2q,2q+1, scans j-half jh ----
  const int q   = tid >> 1;           // 0..255
  const int jh  = tid & 1;            // j-half
  const int r0  = 2*q, r1 = 2*q + 1;

  float best[2][KNN]; int bidx[2][KNN];
#pragma unroll
  for (int r = 0; r < 2; ++r)
#pragma unroll
    for (int m = 0; m < KNN; ++m) { best[r][m] = BIG; bidx[r][m] = 0; }

  float4 xr[2][16];
#pragma unroll
  for (int k4 = 0; k4 < 16; ++k4) {
    xr[0][k4] = *(const float4*)&lds[r0*ST + 4*k4];
    xr[1][k4] = *(const float4*)&lds[r1*ST + 4*k4];
  }

  const int jbase = jh * (NNODE/2);
#pragma unroll 1
  for (int jj = 0; jj < NNODE/2; ++jj) {
    int j = jbase + jj;
    const float* xj = &lds[j*ST];
    float4 a0 = {0,0,0,0}, a1 = {0,0,0,0};
#pragma unroll
    for (int k4 = 0; k4 < 16; ++k4) {
      float4 v = *(const float4*)(xj + 4*k4);   // 2-address broadcast (free)
      a0.x = fmaf(xr[0][k4].x, v.x, a0.x); a0.y = fmaf(xr[0][k4].y, v.y, a0.y);
      a0.z = fmaf(xr[0][k4].z, v.z, a0.z); a0.w = fmaf(xr[0][k4].w, v.w, a0.w);
      a1.x = fmaf(xr[1][k4].x, v.x, a1.x); a1.y = fmaf(xr[1][k4].y, v.y, a1.y);
      a1.z = fmaf(xr[1][k4].z, v.z, a1.z); a1.w = fmaf(xr[1][k4].w, v.w, a1.w);
    }
    float sj = lds[EXTRA + j];
    float e0 = fmaf(-2.f, (a0.x+a0.y)+(a0.z+a0.w), sj);
    float e1 = fmaf(-2.f, (a1.x+a1.y)+(a1.z+a1.w), sj);
    if (j == r0) e0 = BIG;
    if (j == r1) e1 = BIG;
    insert6(best[0], bidx[0], e0, j);
    insert6(best[1], bidx[1], e1, j);
  }

  // ---- merge top-6 with partner lane (other j-half); snapshot first ----
#pragma unroll
  for (int r = 0; r < 2; ++r) {
    float pv[KNN]; int pi[KNN];
#pragma unroll
    for (int m = 0; m < KNN; ++m) {
      pv[m] = __shfl_xor(best[r][m], 1);
      pi[m] = __shfl_xor(bidx[r][m], 1);
    }
#pragma unroll
    for (int m = 0; m < KNN; ++m) insert6(best[r], bidx[r], pv[m], pi[m]);
  }

  // ---- publish canonical neighbor lists (jh==0 lanes) to LDS idx area ----
  if (jh == 0) {
#pragma unroll
    for (int r = 0; r < 2; ++r)
#pragma unroll
      for (int m = 0; m < KNN; ++m)
        ildx[(2*q + r)*KNN + m] = bidx[r][m];
  }
  __syncthreads();

  // owner picks up its row's neighbor list
  int nbrA[KNN];
#pragma unroll
  for (int m = 0; m < KNN; ++m) nbrA[m] = ildx[rA*KNN + m];

  // ---- h = prelu(x@W1+b1); h = prelu(h@W2+b2)  (own row, in place) ----
  linear_row(lds, rA, P.W1, P.b1, P.a1);
  linear_row(lds, rA, P.W2, P.b2, P.a2);

  // ---- 4x gconv: out_i = sum_{m in nbr} (h@W)_m + 6b + h_i ----
  const float* Wcs[4] = {P.Wc0, P.Wc1, P.Wc2, P.Wc3};
  const float* bcs[4] = {P.bc0, P.bc1, P.bc2, P.bc3};
#pragma unroll 1
  for (int cv = 0; cv < 4; ++cv) {
    const float* W = Wcs[cv];
    const float* b = bcs[cv];
    // snapshot own h row (own-thread RAW, no barrier needed)
    float hsA[NF];
#pragma unroll
    for (int k4 = 0; k4 < 16; ++k4) {
      float4 v = *(const float4*)&lds[rA*ST + 4*k4];
      hsA[4*k4]=v.x; hsA[4*k4+1]=v.y; hsA[4*k4+2]=v.z; hsA[4*k4+3]=v.w;
    }
    // p = h @ W, published in place
    {
      float p0[NF];
      gemm64(&lds[rA*ST], W, p0);
#pragma unroll
      for (int o4 = 0; o4 < 16; ++o4) {
        float4 v = {p0[4*o4], p0[4*o4+1], p0[4*o4+2], p0[4*o4+3]};
        *(float4*)&lds[rA*ST + 4*o4] = v;
      }
    }
    __syncthreads();                       // all p-rows published
    // gather: s = sum of 6 neighbor p-rows (init from neighbor 0)
    float sA[NF];
    {
      const float* pr = &lds[nbrA[0]*ST];
#pragma unroll
      for (int o4 = 0; o4 < 16; ++o4) {
        float4 v = *(const float4*)(pr + 4*o4);
        sA[4*o4]=v.x; sA[4*o4+1]=v.y; sA[4*o4+2]=v.z; sA[4*o4+3]=v.w;
      }
    }
#pragma unroll
    for (int m = 1; m < KNN; ++m) {
      const float* pr = &lds[nbrA[m]*ST];
#pragma unroll
      for (int o4 = 0; o4 < 16; ++o4) {
        float4 v = *(const float4*)(pr + 4*o4);
        sA[4*o4]+=v.x; sA[4*o4+1]+=v.y; sA[4*o4+2]+=v.z; sA[4*o4+3]+=v.w;
      }
    }
    __syncthreads();                       // all gathers done before overwrite
#pragma unroll
    for (int o4 = 0; o4 < 16; ++o4) {
      float4 v;
      v.x = sA[4*o4]   + 6.f*b[4*o4]   + hsA[4*o4];
      v.y = sA[4*o4+1] + 6.f*b[4*o4+1] + hsA[4*o4+1];
      v.z = sA[4*o4+2] + 6.f*b[4*o4+2] + hsA[4*o4+2];
      v.w = sA[4*o4+3] + 6.f*b[4*o4+3] + hsA[4*o4+3];
      *(float4*)&lds[rA*ST + 4*o4] = v;
    }
  }

  // ---- last two PReLU linears (own row) ----
  linear_row(lds, rA, P.W3, P.b3, P.a3);
  linear_row(lds, rA, P.W4, P.b4, P.a4);

  __syncthreads();   // all h final before pool reads

  // ---- global add pool: pooled[f] = sum_rows h[r][f]; 8 chunks of 64 rows ----
  {
    int f = tid & 63, c = tid >> 6;      // c in 0..7
    int rstart = c * 64;
    float pa=0.f, pb=0.f, pc=0.f, pd=0.f;
#pragma unroll 1
    for (int r = 0; r < 64; r += 4) {
      pa += lds[(rstart+r  )*ST + f];
      pb += lds[(rstart+r+1)*ST + f];
      pc += lds[(rstart+r+2)*ST + f];
      pd += lds[(rstart+r+3)*ST + f];
    }
    lds[EXTRA + 64 + c*64 + f] = (pa+pb)+(pc+pd);
  }
  __syncthreads();
  if (tid < 64) {
    float pool = 0.f;
#pragma unroll
    for (int c = 0; c < 8; ++c) pool += lds[EXTRA + 64 + c*64 + tid];
    lds[EXTRA + tid] = pool;               // pooled[0..63]
  }
  __syncthreads();

  // ---- head MLP ----
  if (tid < 256) {                         // y1 = leaky(pooled @ Wh1 + bh1), 256 wide
    float acc = P.bh1[tid];
#pragma unroll 4
    for (int k = 0; k < 64; ++k) acc = fmaf(lds[EXTRA+k], P.Wh1[k*256 + tid], acc);
    lds[EXTRA + 576 + tid] = acc >= 0.f ? acc : 0.2f*acc;  // y1 @ EXTRA+576..831
  }
  __syncthreads();
  if (tid < 256) {                         // y2 = leaky(y1 @ Wh2 + bh2), 256 wide
    float acc = P.bh2[tid];
#pragma unroll 4
    for (int k = 0; k < 256; ++k) acc = fmaf(lds[EXTRA+576+k], P.Wh2[k*256 + tid], acc);
    lds[EXTRA + 64 + tid] = acc >= 0.f ? acc : 0.2f*acc;   // y2 @ EXTRA+64..319
  }
  __syncthreads();
  if (tid < 64) {                          // y3 = leaky(y2 @ Wh3 + bh3), 64 wide
    float acc = P.bh3[tid];
#pragma unroll 4
    for (int k = 0; k < 256; ++k) acc = fmaf(lds[EXTRA+64+k], P.Wh3[k*64 + tid], acc);
    lds[EXTRA + 384 + tid] = acc >= 0.f ? acc : 0.2f*acc;
  }
  __syncthreads();
  if (tid == 0) {                          // out[g] = y3 @ Wh4 + bh4
    float acc = P.bh4[0];
#pragma unroll 4
    for (int k = 0; k < 64; ++k) acc = fmaf(lds[EXTRA+384+k], P.Wh4[k], acc);
    P.out[g] = acc;
  }
}

extern "C" void kernel_launch(void* const* d_in, const int* in_sizes, int n_in,
                              void* d_out, int out_size, void* d_ws, size_t ws_size,
                              hipStream_t stream) {
  Params P;
  P.x   = (const float*)d_in[0];
  P.W1  = (const float*)d_in[1];  P.b1  = (const float*)d_in[2];  P.a1 = (const float*)d_in[3];
  P.W2  = (const float*)d_in[4];  P.b2  = (const float*)d_in[5];  P.a2 = (const float*)d_in[6];
  P.Wc0 = (const float*)d_in[7];  P.bc0 = (const float*)d_in[8];
  P.Wc1 = (const float*)d_in[9];  P.bc1 = (const float*)d_in[10];
  P.Wc2 = (const float*)d_in[11]; P.bc2 = (const float*)d_in[12];
  P.Wc3 = (const float*)d_in[13]; P.bc3 = (const float*)d_in[14];
  P.W3  = (const float*)d_in[15]; P.b3  = (const float*)d_in[16]; P.a3 = (const float*)d_in[17];
  P.W4  = (const float*)d_in[18]; P.b4  = (const float*)d_in[19]; P.a4 = (const float*)d_in[20];
  P.Wh1 = (const float*)d_in[21]; P.bh1 = (const float*)d_in[22];
  P.Wh2 = (const float*)d_in[23]; P.bh2 = (const float*)d_in[24];
  P.Wh3 = (const float*)d_in[25]; P.bh3 = (const float*)d_in[26];
  P.Wh4 = (const float*)d_in[27]; P.bh4 = (const float*)d_in[28];
  P.out = (float*)d_out;

  // opt-in for >64KB dynamic LDS (154624 B); idempotent, graph-capture safe
  (void)hipFuncSetAttribute(reinterpret_cast<const void*>(fused_gnn),
                            hipFuncAttributeMaxDynamicSharedMemorySize, LDS_BYTES);

  fused_gnn<<<NGRAPH, NT, LDS_BYTES, stream>>>(P);
}